// Round 11
// baseline (73.618 us; speedup 1.0000x reference)
//
#include <hip/hip_runtime.h>
#include <hip/hip_bf16.h>

// B=8, T=2048, E=1024, H=64
// Round 11:
//  - attn: full-d waves (no dh split): 8 waves = 8 t-tiles x 64 d, 128 t
//    per block, 16 s-chunks of 128 (4 steps of 32 s). Cuts LDS reads/step
//    from 384KB/(64t) to 512KB/(128t) (187->128 B per t*s). Regs: oacc 128
//    AGPR + qf 64 + S/plo/phi staged for ~128 VGPR peak (r6-proven budget).
//  - proj: M=32, K-tile=32, 512 blocks x 256 thr, ring-3 16KB tiles (48KB
//    LDS) -> 2 blocks/CU TLP *and* 2-tile-deep counted vmcnt(4) (r9's TLP +
//    r8/r10's depth). All 4 waves stage 4 units each.
//  - reduce: verified 16-chunk version (partial 32MB bf16 fragment-major).
// Workspace: qb 2MB | kvb 4MB | partial 32MB | Wtb 384KB

typedef __attribute__((ext_vector_type(4))) float f32x4;
typedef __attribute__((ext_vector_type(4))) float float4_t;
typedef __attribute__((ext_vector_type(8))) short short8;
typedef __attribute__((ext_vector_type(4))) unsigned uint4_t;
typedef __attribute__((ext_vector_type(2))) unsigned uint2_t;

#define MFMA32(a, b, c) __builtin_amdgcn_mfma_f32_16x16x32_bf16(a, b, c, 0, 0, 0)

__device__ __forceinline__ short f2bf(float f) {
  unsigned u = __builtin_bit_cast(unsigned, f);
  unsigned r = (u + 0x7FFFu + ((u >> 16) & 1u)) >> 16;  // RNE
  return (short)r;
}

__device__ __forceinline__ unsigned cvt_pk_bf16(float lo, float hi) {
  unsigned r;
  asm volatile("v_cvt_pk_bf16_f32 %0, %1, %2" : "=v"(r) : "v"(lo), "v"(hi));
  return r;  // low16=bf16(lo), high16=bf16(hi)
}

__device__ __forceinline__ void gload16(const short* g, short* l) {
  __builtin_amdgcn_global_load_lds(
      (const __attribute__((address_space(1))) unsigned*)g,
      (__attribute__((address_space(3))) unsigned*)l, 16, 0, 0);
}

// ---------------- Kernel 0: W transpose+convert ----------------
// Wtb[n_global][k] bf16, n_global = wi*64 + n in [0,192), k in [0,1024)
__global__ __launch_bounds__(256) void wprep_kernel(
    const float* __restrict__ Wq, const float* __restrict__ Wk,
    const float* __restrict__ Wv, short* __restrict__ Wtb) {
  int lin = blockIdx.x * 256 + threadIdx.x;  // 24576 threads
  int n = lin & 63;
  int k8 = (lin >> 6) & 127;
  int wi = lin >> 13;
  const float* W = (wi == 0) ? Wq : (wi == 1) ? Wk : Wv;
  short* dst = Wtb + wi * 65536 + n * 1024 + k8 * 8;
#pragma unroll
  for (int i = 0; i < 8; i++) dst[i] = f2bf(W[(k8 * 8 + i) * 64 + n]);
}

// ---------------- Kernel 1: pipelined QKV projection ----------------
// 512 blocks x 256 thr (4 waves). M=32 rows/block, K-tile=32, ring-3 16KB.
// LDS tile = 16 units x 1KB:
//   u<4  : x units (f32), u = rg*2 + h; lane l holds
//          x[m0+rg*16+(l&15)][k0 + 8*(l>>4) + 4h .. +3]
//   u>=4 : W units (bf16), u = 4 + cf (cf=0..11); lane l holds
//          Wtb[cf*16+(l&15)][k0 + 8*(l>>4) .. +7]
// Wave (wr=w&1, wc=w>>1): 16 rows x 96 cols, acc[6]. Both operands use the
// same within-tile k-bijection (k = 8g + j) -> contraction exact.
__device__ __forceinline__ void proj_stage(const float* __restrict__ x,
                                           const short* __restrict__ Wtb,
                                           short* dst, int m0, int k0, int w, int l) {
  const int g = l >> 4, lr = l & 15;
#pragma unroll
  for (int i = 0; i < 4; i++) {
    int u = w * 4 + i;
    if (u < 4) {
      int rg = u >> 1, h = u & 1;
      const float* src = x + (size_t)(m0 + rg * 16 + lr) * 1024 + k0 + g * 8 + h * 4;
      gload16((const short*)src, dst + u * 512);
    } else {
      int cf = u - 4;
      const short* src = Wtb + (cf * 16 + lr) * 1024 + k0 + g * 8;
      gload16(src, dst + u * 512);
    }
  }
}

__device__ __forceinline__ void proj_compute(const short* __restrict__ ldsb,
                                             f32x4 (&acc)[6], int wr, int wc, int l) {
  f32x4 fa = *(const f32x4*)&ldsb[(wr * 2 + 0) * 512 + l * 8];  // k slots g*8+0..3
  f32x4 fb = *(const f32x4*)&ldsb[(wr * 2 + 1) * 512 + l * 8];  // k slots g*8+4..7
  uint4_t u_;
  u_[0] = cvt_pk_bf16(fa[0], fa[1]);
  u_[1] = cvt_pk_bf16(fa[2], fa[3]);
  u_[2] = cvt_pk_bf16(fb[0], fb[1]);
  u_[3] = cvt_pk_bf16(fb[2], fb[3]);
  short8 a = __builtin_bit_cast(short8, u_);
#pragma unroll
  for (int nf = 0; nf < 6; nf++) {
    int cf = wc * 6 + nf;
    short8 bfrag = *(const short8*)&ldsb[(4 + cf) * 512 + l * 8];
    acc[nf] = MFMA32(a, bfrag, acc[nf]);
  }
}

__global__ __launch_bounds__(256, 2) void proj_kernel(
    const float* __restrict__ x, const short* __restrict__ Wtb,
    short* __restrict__ qb, short* __restrict__ kvb) {
  __shared__ __align__(16) short lds[3 * 16 * 512];  // 48KB ring-3
  const int tid = threadIdx.x;
  const int l = tid & 63, w = tid >> 6;
  const int g = l >> 4, lr = l & 15;
  const int wr = w & 1, wc = w >> 1;
  const int m0 = blockIdx.x * 32;

  f32x4 acc[6];
#pragma unroll
  for (int i = 0; i < 6; i++) acc[i] = (f32x4){0.f, 0.f, 0.f, 0.f};

  short* bA = lds;
  short* bB = lds + 8192;
  short* bC = lds + 16384;
  proj_stage(x, Wtb, bA, m0, 0, w, l);
  proj_stage(x, Wtb, bB, m0, 32, w, l);

  for (int I = 0; I < 31; I++) {
    // per wave outstanding at top: 4 (tile I) + 4 (tile I+1) -> vmcnt(4)
    // means tile I landed; never 0 mid-loop.
    asm volatile("s_waitcnt vmcnt(4)" ::: "memory");
    __builtin_amdgcn_s_barrier();
    __builtin_amdgcn_sched_barrier(0);
    if (I + 2 < 32) proj_stage(x, Wtb, bC, m0, (I + 2) * 32, w, l);
    proj_compute(bA, acc, wr, wc, l);
    short* t = bA; bA = bB; bB = bC; bC = t;
  }
  asm volatile("s_waitcnt vmcnt(0)" ::: "memory");
  __builtin_amdgcn_s_barrier();
  __builtin_amdgcn_sched_barrier(0);
  proj_compute(bA, acc, wr, wc, l);

  // epilogue: verified store formulas (wave = 16 rows x 96 cols)
#pragma unroll
  for (int nf = 0; nf < 6; nf++) {
    int colg0 = wc * 96 + nf * 16;
    int wi = colg0 >> 6;
    int d = (colg0 & 63) + lr;
    // fold 1/sqrt(H)*log2(e) into q so attn softmax uses 2^x directly
    float scale = (wi == 0) ? 0.18033688f : 1.0f;
#pragma unroll
    for (int r = 0; r < 4; r++) {
      int row = m0 + wr * 16 + g * 4 + r;
      int b = row >> 11, t = row & 2047;
      short bv = f2bf(acc[nf][r] * scale);
      if (wi == 0) {
        int idx = (((b * 128 + (t >> 4)) * 2 + (d >> 5)) * 64 +
                   ((((d >> 3) & 3) << 4) | (t & 15))) * 8 + (d & 7);
        qb[idx] = bv;
      } else if (wi == 1) {
        int u = (b << 2) | (((t >> 4) & 1) << 1) | (d >> 5);
        int idx = (((t >> 5) * 64 + u) << 9) +
                  ((((((d >> 3) & 3) << 4)) | (t & 15)) << 3) + (d & 7);
        kvb[idx] = bv;
      } else {
        int u = 32 + (b << 2) + (d >> 4);
        int idx = (((t >> 5) * 64 + u) << 9) +
                  (((((t >> 2) & 3) << 4) | (d & 15)) << 3) + (((t >> 4) & 1) << 2) + (t & 3);
        kvb[idx] = bv;
      }
    }
  }
}

// ---------------- Kernel 2: pipelined fused attention ----------------
__device__ __forceinline__ void stage_step(const short* __restrict__ kvb,
                                           short* lds_buf, int w, int l, int W) {
#pragma unroll
  for (int i = 0; i < 8; i++) {
    int u = w * 8 + i;
    const short* src = kvb + (((size_t)W * 64 + u) << 9) + l * 8;
    gload16(src, lds_buf + u * 512);
  }
}

// 256 blocks x 512 thr = 8 waves, each wave = one 16-t tile x FULL 64 d.
// Block: 128 t-rows x one 128-s chunk; 4 steps of 32 s. 16 s-chunks.
__global__ __launch_bounds__(512, 2) void attn_kernel(
    const short* __restrict__ qb, const short* __restrict__ kvb,
    short* __restrict__ partial) {
  __shared__ __align__(16) short lds[2][64 * 512];  // 2 x 64KB ring
  const int tid = threadIdx.x;
  const int l = tid & 63, w = tid >> 6;
  // XCD-aware decode: blocks sharing an s-chunk pair live on one XCD
  const int lin = blockIdx.x;                       // 0..255
  const int sc = (lin & 7) * 2 + ((lin >> 3) & 1);  // 0..15
  const int tblk = lin >> 4;                        // 0..15
  const int tb16 = tblk * 8 + w;                    // 0..127

  // Q hoisted: 16 x b128 (64 VGPR)
  short8 qf[8][2];
#pragma unroll
  for (int b = 0; b < 8; b++)
#pragma unroll
    for (int ks = 0; ks < 2; ks++)
      qf[b][ks] = *(const short8*)&qb[(size_t)((b * 128 + tb16) * 2 + ks) * 512 + l * 8];

  f32x4 oacc[8][4];  // 128 AGPR
#pragma unroll
  for (int b = 0; b < 8; b++)
#pragma unroll
    for (int df = 0; df < 4; df++) oacc[b][df] = (f32x4){0.f, 0.f, 0.f, 0.f};

  stage_step(kvb, &lds[0][0], w, l, sc * 4);

  for (int it = 0; it < 4; it++) {
    __syncthreads();  // drains step-old staging (free), publishes buf[it]
    if (it + 1 < 4) stage_step(kvb, &lds[(it + 1) & 1][0], w, l, sc * 4 + it + 1);
    const short* ldsc = &lds[it & 1][0];

    uint2_t plo[8], phi[8];
#pragma unroll
    for (int sf = 0; sf < 2; sf++) {
      f32x4 S[8];
      __builtin_amdgcn_s_setprio(1);
#pragma unroll
      for (int b = 0; b < 8; b++) {
        short8 kf0 = *(const short8*)&ldsc[(b * 4 + sf * 2 + 0) * 512 + l * 8];
        short8 kf1 = *(const short8*)&ldsc[(b * 4 + sf * 2 + 1) * 512 + l * 8];
        f32x4 s = (f32x4){0.f, 0.f, 0.f, 0.f};
        s = MFMA32(kf0, qf[b][0], s);
        s = MFMA32(kf1, qf[b][1], s);
        S[b] = s;
      }
      __builtin_amdgcn_s_setprio(0);
      // softmax over batch (elementwise across the 8 register sets)
#pragma unroll
      for (int r = 0; r < 4; r++) {
        float den = 0.f;
#pragma unroll
        for (int b = 0; b < 8; b++) {
          float e = __builtin_amdgcn_exp2f(S[b][r]);
          S[b][r] = e;
          den += e;
        }
        float inv = __builtin_amdgcn_rcpf(den);
#pragma unroll
        for (int b = 0; b < 8; b++) S[b][r] *= inv;
      }
#pragma unroll
      for (int b = 0; b < 8; b++) {
        uint2_t pw;
        pw[0] = cvt_pk_bf16(S[b][0], S[b][1]);
        pw[1] = cvt_pk_bf16(S[b][2], S[b][3]);
        if (sf == 0) plo[b] = pw; else phi[b] = pw;
      }
    }
    // PV k=32, full d: A = V unit (16 d x 32 s, sigma-map), B = packed P
    __builtin_amdgcn_s_setprio(1);
#pragma unroll
    for (int b = 0; b < 8; b++) {
      uint4_t pu;
      pu[0] = plo[b][0]; pu[1] = plo[b][1]; pu[2] = phi[b][0]; pu[3] = phi[b][1];
      short8 pbv = __builtin_bit_cast(short8, pu);
#pragma unroll
      for (int df = 0; df < 4; df++) {
        short8 vf = *(const short8*)&ldsc[(32 + b * 4 + df) * 512 + l * 8];
        oacc[b][df] = MFMA32(vf, pbv, oacc[b][df]);
      }
    }
    __builtin_amdgcn_s_setprio(0);
  }

  // store bf16 partial fragment-major (uint2/lane, wave-contiguous 512B runs)
  uint2_t* pout = (uint2_t*)partial;
#pragma unroll
  for (int b = 0; b < 8; b++)
#pragma unroll
    for (int df = 0; df < 4; df++) {
      uint2_t pk;
      pk[0] = cvt_pk_bf16(oacc[b][df][0], oacc[b][df][1]);
      pk[1] = cvt_pk_bf16(oacc[b][df][2], oacc[b][df][3]);
      __builtin_nontemporal_store(
          pk, &pout[(size_t)(((sc * 8 + b) * 128 + tb16) * 4 + df) * 64 + l]);
    }
}

// ---------------- Kernel 3: reduce bf16 partials -> f32 out ----------------
__global__ __launch_bounds__(256) void reduce_kernel(const short* __restrict__ partial,
                                                     float* __restrict__ out) {
  int i = blockIdx.x * 256 + threadIdx.x;  // 0..262143: (b,tb16,df,l)
  const uint2_t* p = (const uint2_t*)partial;
  float4_t a = (float4_t){0.f, 0.f, 0.f, 0.f};
  for (int sc = 0; sc < 16; sc++) {
    uint2_t v = __builtin_nontemporal_load(&p[(size_t)sc * 262144 + i]);
    a[0] += __builtin_bit_cast(float, v[0] << 16);
    a[1] += __builtin_bit_cast(float, v[0] & 0xFFFF0000u);
    a[2] += __builtin_bit_cast(float, v[1] << 16);
    a[3] += __builtin_bit_cast(float, v[1] & 0xFFFF0000u);
  }
  int b = i >> 15;
  int r1 = i & 32767;
  int tb16 = r1 >> 8;
  int r2 = r1 & 255;
  int df = r2 >> 6;
  int ll = r2 & 63;
  int gg = ll >> 4, lrr = ll & 15;
  *(float4_t*)&out[(size_t)(b * 2048 + tb16 * 16 + lrr) * 64 + df * 16 + gg * 4] = a;
}

extern "C" void kernel_launch(void* const* d_in, const int* in_sizes, int n_in,
                              void* d_out, int out_size, void* d_ws, size_t ws_size,
                              hipStream_t stream) {
  const float* x = (const float*)d_in[0];
  const float* Wq = (const float*)d_in[1];
  const float* Wk = (const float*)d_in[2];
  const float* Wv = (const float*)d_in[3];
  float* out = (float*)d_out;

  char* ws = (char*)d_ws;
  short* qb = (short*)ws;                     // 2MB
  short* kvb = qb + 16384 * 64;               // 4MB (64 windows x 64 units)
  short* partial = kvb + 2 * 16384 * 64;      // 32MB bf16 fragment-major (16 sc)
  short* Wtb = partial + 16ull * 262144 * 4;  // 384KB

  wprep_kernel<<<96, 256, 0, stream>>>(Wq, Wk, Wv, Wtb);
  proj_kernel<<<512, 256, 0, stream>>>(x, Wtb, qb, kvb);
  attn_kernel<<<256, 512, 0, stream>>>(qb, kvb, partial);
  reduce_kernel<<<1024, 256, 0, stream>>>(partial, out);
}

// Round 12
// 62.759 us; speedup vs baseline: 1.1730x; 1.1730x over previous
//
#include <hip/hip_runtime.h>
#include <hip/hip_bf16.h>

// B=8, T=2048, E=1024, H=64
// Round 12: r10 baseline (best 63.0us) with ONE change: proj ring-4 LDS
// (80KB) with 3-tile-deep counted-vmcnt prefetch (vmcnt(10) steady state,
// 5/0 tail) -- prefetch cover ~3x step-time vs the marginal 2x of r8/r10.
// M=64/256-block kept (M=32/512-block costs +10.5us: r9/r11 A/B evidence).
// attn (dh-split, 8x32-s steps, 256-s chunks), 16MB bf16 partial, 8-deep
// reduce, wprep: byte-identical to r10.
//
// Workspace: qb 2MB | kvb 4MB | partial 16MB | Wtb 384KB

typedef __attribute__((ext_vector_type(4))) float f32x4;
typedef __attribute__((ext_vector_type(4))) float float4_t;
typedef __attribute__((ext_vector_type(8))) short short8;
typedef __attribute__((ext_vector_type(4))) unsigned uint4_t;
typedef __attribute__((ext_vector_type(2))) unsigned uint2_t;

#define MFMA32(a, b, c) __builtin_amdgcn_mfma_f32_16x16x32_bf16(a, b, c, 0, 0, 0)

__device__ __forceinline__ short f2bf(float f) {
  unsigned u = __builtin_bit_cast(unsigned, f);
  unsigned r = (u + 0x7FFFu + ((u >> 16) & 1u)) >> 16;  // RNE
  return (short)r;
}

__device__ __forceinline__ unsigned cvt_pk_bf16(float lo, float hi) {
  unsigned r;
  asm volatile("v_cvt_pk_bf16_f32 %0, %1, %2" : "=v"(r) : "v"(lo), "v"(hi));
  return r;  // low16=bf16(lo), high16=bf16(hi)
}

__device__ __forceinline__ void gload16(const short* g, short* l) {
  __builtin_amdgcn_global_load_lds(
      (const __attribute__((address_space(1))) unsigned*)g,
      (__attribute__((address_space(3))) unsigned*)l, 16, 0, 0);
}

// ---------------- Kernel 0: W transpose+convert ----------------
// Wtb[n_global][k] bf16, n_global = wi*64 + n in [0,192), k in [0,1024)
__global__ __launch_bounds__(256) void wprep_kernel(
    const float* __restrict__ Wq, const float* __restrict__ Wk,
    const float* __restrict__ Wv, short* __restrict__ Wtb) {
  int lin = blockIdx.x * 256 + threadIdx.x;  // 24576 threads
  int n = lin & 63;
  int k8 = (lin >> 6) & 127;
  int wi = lin >> 13;
  const float* W = (wi == 0) ? Wq : (wi == 1) ? Wk : Wv;
  short* dst = Wtb + wi * 65536 + n * 1024 + k8 * 8;
#pragma unroll
  for (int i = 0; i < 8; i++) dst[i] = f2bf(W[(k8 * 8 + i) * 64 + n]);
}

// ---------------- Kernel 1: pipelined QKV projection ----------------
// 256 blocks x 512 thr (8 waves). M=64 rows/block, K-tile=32, ring-4 80KB.
// LDS tile = 20 units x 1KB:
//   u<8  : x units (f32), u = xwr*2 + h; lane l holds
//          x[m0+xwr*16+(l&15)][k0 + 8*(l>>4) + 4h .. +3]
//   u>=8 : W units (bf16), u = 8 + cf (cf=0..11); lane l holds
//          Wtb[cf*16+(l&15)][k0 + 8*(l>>4) .. +7]
// Wave (wr=w&3, wc=w>>2): 16 rows x 96 cols, acc[6]. Both operands use the
// same within-tile k-bijection (k = 8g + j) -> contraction exact.
__device__ __forceinline__ void proj_stage(const float* __restrict__ x,
                                           const short* __restrict__ Wtb,
                                           short* dst, int m0, int k0, int w, int l) {
  const int g = l >> 4, lr = l & 15;
  if (w < 4) {
#pragma unroll
    for (int i = 0; i < 5; i++) {
      int u = w * 5 + i;
      if (u < 8) {
        int xwr = u >> 1, h = u & 1;
        const float* src = x + (size_t)(m0 + xwr * 16 + lr) * 1024 + k0 + g * 8 + h * 4;
        gload16((const short*)src, dst + u * 512);
      } else {
        int cf = u - 8;
        const short* src = Wtb + (cf * 16 + lr) * 1024 + k0 + g * 8;
        gload16(src, dst + u * 512);
      }
    }
  }
}

__device__ __forceinline__ void proj_compute(const short* __restrict__ ldsb,
                                             f32x4 (&acc)[6], int wr, int wc, int l) {
  f32x4 fa = *(const f32x4*)&ldsb[(wr * 2 + 0) * 512 + l * 8];  // k slots g*8+0..3
  f32x4 fb = *(const f32x4*)&ldsb[(wr * 2 + 1) * 512 + l * 8];  // k slots g*8+4..7
  uint4_t u_;
  u_[0] = cvt_pk_bf16(fa[0], fa[1]);
  u_[1] = cvt_pk_bf16(fa[2], fa[3]);
  u_[2] = cvt_pk_bf16(fb[0], fb[1]);
  u_[3] = cvt_pk_bf16(fb[2], fb[3]);
  short8 a = __builtin_bit_cast(short8, u_);
#pragma unroll
  for (int nf = 0; nf < 6; nf++) {
    int cf = wc * 6 + nf;
    short8 bfrag = *(const short8*)&ldsb[(8 + cf) * 512 + l * 8];
    acc[nf] = MFMA32(a, bfrag, acc[nf]);
  }
}

__global__ __launch_bounds__(512) void proj_kernel(
    const float* __restrict__ x, const short* __restrict__ Wtb,
    short* __restrict__ qb, short* __restrict__ kvb) {
  __shared__ __align__(16) short lds[4 * 20 * 512];  // 80KB ring-4
  const int tid = threadIdx.x;
  const int l = tid & 63, w = tid >> 6;
  const int g = l >> 4, lr = l & 15;
  const int wr = w & 3, wc = w >> 2;
  const int m0 = blockIdx.x * 64;

  f32x4 acc[6];
#pragma unroll
  for (int i = 0; i < 6; i++) acc[i] = (f32x4){0.f, 0.f, 0.f, 0.f};

  short* b0 = lds;
  short* b1 = lds + 10240;
  short* b2 = lds + 20480;
  short* b3 = lds + 30720;
  // prologue: 3 tiles in flight (15 loads/wave for w<4)
  proj_stage(x, Wtb, b0, m0, 0, w, l);
  proj_stage(x, Wtb, b1, m0, 32, w, l);
  proj_stage(x, Wtb, b2, m0, 64, w, l);

  for (int I = 0; I < 30; I++) {
    // outstanding/wave (w<4) at top: rem(I) + 5(I+1) + 5(I+2) ->
    // vmcnt(10) == tile I landed; never 0 mid-loop.
    asm volatile("s_waitcnt vmcnt(10)" ::: "memory");
    __builtin_amdgcn_s_barrier();
    __builtin_amdgcn_sched_barrier(0);
    if (I + 3 < 32) proj_stage(x, Wtb, b3, m0, (I + 3) * 32, w, l);
    proj_compute(b0, acc, wr, wc, l);
    short* t = b0; b0 = b1; b1 = b2; b2 = b3; b3 = t;
  }
  // I=30: only tile 31's 5 loads younger -> vmcnt(5) == tile 30 landed
  asm volatile("s_waitcnt vmcnt(5)" ::: "memory");
  __builtin_amdgcn_s_barrier();
  __builtin_amdgcn_sched_barrier(0);
  proj_compute(b0, acc, wr, wc, l);
  { short* t = b0; b0 = b1; b1 = b2; b2 = b3; b3 = t; }
  // I=31: drain
  asm volatile("s_waitcnt vmcnt(0)" ::: "memory");
  __builtin_amdgcn_s_barrier();
  __builtin_amdgcn_sched_barrier(0);
  proj_compute(b0, acc, wr, wc, l);

  // epilogue: verified store formulas (wave = 16 rows x 96 cols)
#pragma unroll
  for (int nf = 0; nf < 6; nf++) {
    int colg0 = wc * 96 + nf * 16;
    int wi = colg0 >> 6;
    int d = (colg0 & 63) + lr;
    // fold 1/sqrt(H)*log2(e) into q so attn softmax uses 2^x directly
    float scale = (wi == 0) ? 0.18033688f : 1.0f;
#pragma unroll
    for (int r = 0; r < 4; r++) {
      int row = m0 + wr * 16 + g * 4 + r;
      int b = row >> 11, t = row & 2047;
      short bv = f2bf(acc[nf][r] * scale);
      if (wi == 0) {
        int idx = (((b * 128 + (t >> 4)) * 2 + (d >> 5)) * 64 +
                   ((((d >> 3) & 3) << 4) | (t & 15))) * 8 + (d & 7);
        qb[idx] = bv;
      } else if (wi == 1) {
        int u = (b << 2) | (((t >> 4) & 1) << 1) | (d >> 5);
        int idx = (((t >> 5) * 64 + u) << 9) +
                  ((((((d >> 3) & 3) << 4)) | (t & 15)) << 3) + (d & 7);
        kvb[idx] = bv;
      } else {
        int u = 32 + (b << 2) + (d >> 4);
        int idx = (((t >> 5) * 64 + u) << 9) +
                  (((((t >> 2) & 3) << 4) | (d & 15)) << 3) + (((t >> 4) & 1) << 2) + (t & 3);
        kvb[idx] = bv;
      }
    }
  }
}

// ---------------- Kernel 2: pipelined fused attention ----------------
__device__ __forceinline__ void stage_step(const short* __restrict__ kvb,
                                           short* lds_buf, int w, int l, int W) {
#pragma unroll
  for (int i = 0; i < 8; i++) {
    int u = w * 8 + i;
    const short* src = kvb + (((size_t)W * 64 + u) << 9) + l * 8;
    gload16(src, lds_buf + u * 512);
  }
}

// 256 blocks x 512 thr = 8 waves: tt = w>>1 (4 t-tiles of 16), dh = w&1.
// Block: 64 t-rows x one 256-s chunk; 8 steps of 32 s. sc = xcd (lin&7).
__global__ __launch_bounds__(512, 2) void attn_kernel(
    const short* __restrict__ qb, const short* __restrict__ kvb,
    short* __restrict__ partial) {
  __shared__ __align__(16) short lds[2][64 * 512];  // 2 x 64KB ring
  const int tid = threadIdx.x;
  const int l = tid & 63, w = tid >> 6;
  const int tt = w >> 1, dh = w & 1;
  const int lin = blockIdx.x;     // 0..255
  const int sc = lin & 7;         // 0..7: per-XCD s-chunk of 256
  const int tblk = lin >> 3;      // 0..31
  const int tb16 = tblk * 4 + tt; // 0..127

  // Q hoisted: 16 x b128
  short8 qf[8][2];
#pragma unroll
  for (int b = 0; b < 8; b++)
#pragma unroll
    for (int ks = 0; ks < 2; ks++)
      qf[b][ks] = *(const short8*)&qb[(size_t)((b * 128 + tb16) * 2 + ks) * 512 + l * 8];

  f32x4 oacc[8][2];
#pragma unroll
  for (int b = 0; b < 8; b++)
#pragma unroll
    for (int n = 0; n < 2; n++) oacc[b][n] = (f32x4){0.f, 0.f, 0.f, 0.f};

  stage_step(kvb, &lds[0][0], w, l, sc * 8);

  for (int it = 0; it < 8; it++) {
    __syncthreads();  // drains step-old staging (free), publishes buf[it]
    if (it + 1 < 8) stage_step(kvb, &lds[(it + 1) & 1][0], w, l, sc * 8 + it + 1);
    const short* ldsc = &lds[it & 1][0];

    uint2_t plo[8], phi[8];
#pragma unroll
    for (int sf = 0; sf < 2; sf++) {
      f32x4 S[8];
      __builtin_amdgcn_s_setprio(1);
#pragma unroll
      for (int b = 0; b < 8; b++) {
        short8 kf0 = *(const short8*)&ldsc[(b * 4 + sf * 2 + 0) * 512 + l * 8];
        short8 kf1 = *(const short8*)&ldsc[(b * 4 + sf * 2 + 1) * 512 + l * 8];
        f32x4 s = (f32x4){0.f, 0.f, 0.f, 0.f};
        s = MFMA32(kf0, qf[b][0], s);
        s = MFMA32(kf1, qf[b][1], s);
        S[b] = s;
      }
      __builtin_amdgcn_s_setprio(0);
      // softmax over batch (elementwise across the 8 register sets)
#pragma unroll
      for (int r = 0; r < 4; r++) {
        float den = 0.f;
#pragma unroll
        for (int b = 0; b < 8; b++) {
          float e = __builtin_amdgcn_exp2f(S[b][r]);
          S[b][r] = e;
          den += e;
        }
        float inv = __builtin_amdgcn_rcpf(den);
#pragma unroll
        for (int b = 0; b < 8; b++) S[b][r] *= inv;
      }
#pragma unroll
      for (int b = 0; b < 8; b++) {
        uint2_t pw;
        pw[0] = cvt_pk_bf16(S[b][0], S[b][1]);
        pw[1] = cvt_pk_bf16(S[b][2], S[b][3]);
        if (sf == 0) plo[b] = pw; else phi[b] = pw;
      }
    }
    // PV k=32: A = V unit (16 d x 32 s, sigma-map), B = packed P
    __builtin_amdgcn_s_setprio(1);
#pragma unroll
    for (int b = 0; b < 8; b++) {
      uint4_t pu;
      pu[0] = plo[b][0]; pu[1] = plo[b][1]; pu[2] = phi[b][0]; pu[3] = phi[b][1];
      short8 pbv = __builtin_bit_cast(short8, pu);
      short8 vf0 = *(const short8*)&ldsc[(32 + b * 4 + dh * 2 + 0) * 512 + l * 8];
      short8 vf1 = *(const short8*)&ldsc[(32 + b * 4 + dh * 2 + 1) * 512 + l * 8];
      oacc[b][0] = MFMA32(vf0, pbv, oacc[b][0]);
      oacc[b][1] = MFMA32(vf1, pbv, oacc[b][1]);
    }
    __builtin_amdgcn_s_setprio(0);
  }

  // store bf16 partial fragment-major (uint2/lane, wave-contiguous 512B runs)
  uint2_t* pout = (uint2_t*)partial;
#pragma unroll
  for (int b = 0; b < 8; b++)
#pragma unroll
    for (int n = 0; n < 2; n++) {
      int df = dh * 2 + n;
      uint2_t pk;
      pk[0] = cvt_pk_bf16(oacc[b][n][0], oacc[b][n][1]);
      pk[1] = cvt_pk_bf16(oacc[b][n][2], oacc[b][n][3]);
      __builtin_nontemporal_store(
          pk, &pout[(size_t)(((sc * 8 + b) * 128 + tb16) * 4 + df) * 64 + l]);
    }
}

// ---------------- Kernel 3: reduce bf16 partials -> f32 out ----------------
__global__ __launch_bounds__(256) void reduce_kernel(const short* __restrict__ partial,
                                                     float* __restrict__ out) {
  int i = blockIdx.x * 256 + threadIdx.x;  // 0..262143: (b,tb16,df,l)
  const uint2_t* p = (const uint2_t*)partial;
  float4_t a = (float4_t){0.f, 0.f, 0.f, 0.f};
  for (int sc = 0; sc < 8; sc++) {
    uint2_t v = __builtin_nontemporal_load(&p[(size_t)sc * 262144 + i]);
    a[0] += __builtin_bit_cast(float, v[0] << 16);
    a[1] += __builtin_bit_cast(float, v[0] & 0xFFFF0000u);
    a[2] += __builtin_bit_cast(float, v[1] << 16);
    a[3] += __builtin_bit_cast(float, v[1] & 0xFFFF0000u);
  }
  int b = i >> 15;
  int r1 = i & 32767;
  int tb16 = r1 >> 8;
  int r2 = r1 & 255;
  int df = r2 >> 6;
  int ll = r2 & 63;
  int gg = ll >> 4, lrr = ll & 15;
  *(float4_t*)&out[(size_t)(b * 2048 + tb16 * 16 + lrr) * 64 + df * 16 + gg * 4] = a;
}

extern "C" void kernel_launch(void* const* d_in, const int* in_sizes, int n_in,
                              void* d_out, int out_size, void* d_ws, size_t ws_size,
                              hipStream_t stream) {
  const float* x = (const float*)d_in[0];
  const float* Wq = (const float*)d_in[1];
  const float* Wk = (const float*)d_in[2];
  const float* Wv = (const float*)d_in[3];
  float* out = (float*)d_out;

  char* ws = (char*)d_ws;
  short* qb = (short*)ws;                     // 2MB
  short* kvb = qb + 16384 * 64;               // 4MB (64 windows x 64 units)
  short* partial = kvb + 2 * 16384 * 64;      // 16MB bf16 fragment-major
  short* Wtb = partial + 8ull * 262144 * 4;   // 384KB

  wprep_kernel<<<96, 256, 0, stream>>>(Wq, Wk, Wv, Wtb);
  proj_kernel<<<256, 512, 0, stream>>>(x, Wtb, qb, kvb);
  attn_kernel<<<256, 512, 0, stream>>>(qb, kvb, partial);
  reduce_kernel<<<1024, 256, 0, stream>>>(partial, out);
}